// Round 1
// 113.396 us; speedup vs baseline: 1.1128x; 1.1128x over previous
//
#include <hip/hip_runtime.h>
#include <math.h>

#define S_LEN 2048
#define BSZ 2
#define DM 512
#define NH 8
#define HD 64
#define RTOT (S_LEN*BSZ)             // 4096 rows, row r = s*BSZ + b
#define T_KEEP 32
#define ROW0 ((S_LEN - T_KEEP)*BSZ)  // 4032
#define NXELEM (RTOT*DM)             // 2097152
#define NWROW  (NH*128)              // 1024 (per-head q|k rows)
#define NWELEM (NWROW*DM)            // 524288

typedef __attribute__((ext_vector_type(8))) _Float16 half8;
typedef __attribute__((ext_vector_type(4))) float floatx4;

__device__ __forceinline__ void gld16(const void* g, void* l) {
    __builtin_amdgcn_global_load_lds((const __attribute__((address_space(1))) void*)g,
                                     (__attribute__((address_space(3))) void*)l, 16, 0, 0);
}

__device__ __forceinline__ short cvt1(float v) {
    _Float16 h = (_Float16)v;
    return __builtin_bit_cast(short, h);
}

// ---- Kernel 0: fp32 -> fp16 planes (x, Wq|Wk per head) + zero sbar/Ssum + bg out fill
__global__ __launch_bounds__(256) void convert(
    const float* __restrict__ x,
    const float* __restrict__ Wq, const float* __restrict__ Wk,
    const float* __restrict__ bo,
    short* __restrict__ xf, short* __restrict__ wf,
    float* __restrict__ sbar, float* __restrict__ Ssum,
    float* __restrict__ out)
{
    const int g = blockIdx.x*blockDim.x + threadIdx.x;
    const int stride = gridDim.x*blockDim.x;
    const int total4 = (NXELEM + NWELEM)/4;
    for (int i = g; i < total4; i += stride) {
        float4 v; size_t dst; short* d;
        if (i < NXELEM/4) {
            v = ((const float4*)x)[i];
            dst = (size_t)i*4; d = xf;
        } else {
            int e = (i - NXELEM/4)*4;
            int R = e >> 9;                 // 0..1023: h*128 + (q:0-63 | k:64-127)
            int k = e & 511;
            int h = R >> 7;
            int p = R & 127;
            int m = p >> 6;                 // 0=q, 1=k
            int c = p & 63;
            const float* W = m ? Wk : Wq;
            v = *(const float4*)&W[(size_t)(h*HD + c)*DM + k];
            dst = (size_t)R*DM + k; d = wf;
        }
        short4 hv;
        hv.x = cvt1(v.x); hv.y = cvt1(v.y); hv.z = cvt1(v.z); hv.w = cvt1(v.w);
        *(short4*)&d[dst] = hv;
    }
    // background fill: rows < ROW0 of out are just bo
    {
        const float4* b4 = (const float4*)bo;
        float4* o4 = (float4*)out;
        const int fill4 = ROW0*DM/4;
        for (int i = g; i < fill4; i += stride) o4[i] = b4[i & 127];
    }
    if (g < 16*DM) sbar[g] = 0.f;     // 8192
    if (g < 16)    Ssum[g] = 0.f;
}

// ---- Kernel 1 (FUSED): per-head full q|k GEMM -> sigmoid -> sbar/Ssum/qsel ----
// grid 256 linear = (xcd-swizzled rc 0..31) x (h 0..7); 1 block/CU.
// Block handles 128 rows x all 128 j of one head. B staged in K-quarters
// (2x32KB LDS double-buffer, slot-XOR swizzled via pre-swizzled global src).
// Each wave owns 2 row-tiles -> every B-fragment feeds 2 MFMAs.
// Epilogue: in-register q.k reduce, sigmoid, qsel write, sbar/Ssum atomics.
__global__ __launch_bounds__(256, 1) void qk_sig(
    const _Float16* __restrict__ xf, const _Float16* __restrict__ wf,
    const float* __restrict__ x,
    const float* __restrict__ bq, const float* __restrict__ bk,
    const float* __restrict__ beta,
    float* __restrict__ sbar, float* __restrict__ Ssum,
    float* __restrict__ qsel)
{
    __shared__ __align__(16) char smem[65536];   // 2 x 32KB B quarters; reused for sigma

    const int tid  = threadIdx.x;
    const int w    = tid >> 6;
    const int lane = tid & 63;
    const int lrow = lane & 15;
    const int lk8  = lane >> 4;
    const int bid  = blockIdx.x;
    // XCD-contiguous rc: xcd = bid&7 gets rc in [xcd*4, xcd*4+4) -> xf stays in that XCD's L2
    const int rc   = (bid & 7)*4 + (bid >> 6);
    const int h    = (bid >> 3) & 7;
    const int r0   = rc * 128;

    // staging: chunk c = w*8+i holds B rows j=4c..4c+3 (256B/row, 16 slots of 16B).
    // LDS slot s of row j holds GLOBAL slot s ^ ((j&3)<<2)  (pre-swizzled source).
    const int jsub  = lk8;                          // 0..3: row within chunk
    const int sslot = lrow ^ (jsub << 2);           // global 16B slot this lane fetches
    const _Float16* wsrc = wf + (size_t)(h*128 + w*32 + jsub)*DM + sslot*8;

    // prologue: stage quarter 0
    #pragma unroll
    for (int i = 0; i < 8; ++i)
        gld16(wsrc + (size_t)(4*i)*DM, smem + (w*8 + i)*1024);

    const int rbA = r0 + w*16;
    const int rbB = r0 + (w+4)*16;
    const _Float16* paA = xf + (size_t)(rbA + lrow)*DM + lk8*8;
    const _Float16* paB = xf + (size_t)(rbB + lrow)*DM + lk8*8;

    floatx4 acc[2][8];
    #pragma unroll
    for (int jt = 0; jt < 8; ++jt) { acc[0][jt] = (floatx4)0.f; acc[1][jt] = (floatx4)0.f; }

    half8 Aa[2][4], Ab[2][4];
    #pragma unroll
    for (int kc2 = 0; kc2 < 4; ++kc2) {
        Aa[0][kc2] = *(const half8*)(paA + kc2*32);
        Ab[0][kc2] = *(const half8*)(paB + kc2*32);
    }

    __syncthreads();

    #pragma unroll
    for (int kq = 0; kq < 4; ++kq) {
        const int cur = kq & 1, nxt = cur ^ 1;
        if (kq < 3) {
            // prefetch next-quarter A (regs) and B (LDS) BEFORE MFMAs: the MFMA's
            // wait on current A doesn't drain these (they are newer in vmcnt order)
            #pragma unroll
            for (int kc2 = 0; kc2 < 4; ++kc2) {
                Aa[nxt][kc2] = *(const half8*)(paA + ((kq+1)*4 + kc2)*32);
                Ab[nxt][kc2] = *(const half8*)(paB + ((kq+1)*4 + kc2)*32);
            }
            char* nb = smem + nxt*32768;
            #pragma unroll
            for (int i = 0; i < 8; ++i)
                gld16(wsrc + (size_t)(4*i)*DM + (kq+1)*128, nb + (w*8 + i)*1024);
        }
        const char* buf = smem + cur*32768;
        #pragma unroll
        for (int kc2 = 0; kc2 < 4; ++kc2) {
            #pragma unroll
            for (int jt = 0; jt < 8; ++jt) {
                const int j = jt*16 + lrow;
                const int slotp = (kc2*4 + lk8) ^ ((lrow & 3) << 2);
                half8 bf = *(const half8*)(buf + j*256 + slotp*16);
                acc[0][jt] = __builtin_amdgcn_mfma_f32_16x16x32_f16(Aa[cur][kc2], bf, acc[0][jt], 0, 0, 0);
                acc[1][jt] = __builtin_amdgcn_mfma_f32_16x16x32_f16(Ab[cur][kc2], bf, acc[1][jt], 0, 0, 0);
            }
        }
        __syncthreads();
    }

    // ---- epilogue: sigma = sigmoid((q+bq).(k+bk) * isc); qsel for selected rows
    float* s_sig = (float*)smem;     // B no longer needed; reuse LDS
    float bqv[4], bkv[4];
    #pragma unroll
    for (int jt = 0; jt < 4; ++jt) {
        bqv[jt] = bq[h*HD + jt*16 + lrow];
        bkv[jt] = bk[h*HD + jt*16 + lrow];
    }
    const float isc = 1.0f / (8.0f * expf(beta[h]));

    #pragma unroll
    for (int t = 0; t < 2; ++t) {
        #pragma unroll
        for (int r = 0; r < 4; ++r) {
            float q[4]; float p = 0.f;
            #pragma unroll
            for (int jt = 0; jt < 4; ++jt) {
                float qv = acc[t][jt][r]   + bqv[jt];
                float kv = acc[t][jt+4][r] + bkv[jt];
                q[jt] = qv;
                p += qv * kv;
            }
            p += __shfl_xor(p, 1, 64);
            p += __shfl_xor(p, 2, 64);
            p += __shfl_xor(p, 4, 64);
            p += __shfl_xor(p, 8, 64);
            const int rowl = (w + t*4)*16 + lk8*4 + r;    // 0..127 within block
            if (lrow == 0)
                s_sig[rowl] = 1.0f / (1.0f + expf(-p * isc));
            if (rowl >= 126) {                            // s%64==63 rows (b=0,1)
                const int b = rowl & 1;
                float* qd = &qsel[((size_t)((b*NH + h)*T_KEEP) + rc)*64];
                #pragma unroll
                for (int jt = 0; jt < 4; ++jt) qd[jt*16 + lrow] = q[jt];
            }
        }
    }
    __syncthreads();

    // ---- sbar partial from fp32 x (L2-hot rows); thread = (b, 4-col group)
    {
        const int b  = tid & 1;
        const int cg = tid >> 1;
        const float* px = x + (size_t)(r0 + b)*DM + cg*4;
        float a0=0.f, a1=0.f, a2=0.f, a3=0.f;
        #pragma unroll 8
        for (int si = 0; si < 64; ++si) {
            const float sg = s_sig[si*2 + b];
            const float4 xv = *(const float4*)(px + (size_t)(si*2)*DM);
            a0 += sg*xv.x; a1 += sg*xv.y; a2 += sg*xv.z; a3 += sg*xv.w;
        }
        float* sd = &sbar[(size_t)(b*NH + h)*DM + cg*4];
        atomicAdd(sd+0, a0); atomicAdd(sd+1, a1);
        atomicAdd(sd+2, a2); atomicAdd(sd+3, a3);
    }
    if (tid < 2) {
        float s = 0.f;
        for (int i = 0; i < 64; ++i) s += s_sig[i*2 + tid];
        atomicAdd(&Ssum[tid*NH + h], s);
    }
}

// ---- Kernel 2: kbar/vbar = W*sbar + b*S; coef softmax (kv=0 blocks) ----------
// grid 32 (z x {k,v}), block 256.
__global__ __launch_bounds__(256) void kvbar_coef(
    const float* __restrict__ sbar, const float* __restrict__ Ssum,
    const float* __restrict__ Wk, const float* __restrict__ bk,
    const float* __restrict__ Wv, const float* __restrict__ bv,
    const float* __restrict__ qsel, const float* __restrict__ beta,
    float* __restrict__ vbar, float* __restrict__ coef)
{
    const int z  = blockIdx.x >> 1;
    const int kv = blockIdx.x & 1;
    const int h  = z & 7;
    const int tid = threadIdx.x;

    __shared__ float s_sb[DM];
    __shared__ float s_red[64][4];
    __shared__ float s_kb[64];
    __shared__ float s_part[T_KEEP][8];

    s_sb[tid]       = sbar[z*DM + tid];
    s_sb[tid + 256] = sbar[z*DM + 256 + tid];
    __syncthreads();
    const float S = Ssum[z];

    const float* W    = kv ? Wv : Wk;
    const float* bvec = kv ? bv : bk;
    {
        const int j = tid >> 2, kp = tid & 3;
        const float* wr = &W[(size_t)(h*HD + j)*DM + kp*128];
        float a = 0.f;
        #pragma unroll
        for (int k = 0; k < 128; k += 4) {
            float4 w4 = *(const float4*)&wr[k];
            int k0 = kp*128 + k;
            a += w4.x*s_sb[k0] + w4.y*s_sb[k0+1] + w4.z*s_sb[k0+2] + w4.w*s_sb[k0+3];
        }
        s_red[j][kp] = a;
    }
    __syncthreads();
    if (tid < 64) {
        float val = s_red[tid][0]+s_red[tid][1]+s_red[tid][2]+s_red[tid][3]
                  + bvec[h*HD + tid]*S;
        if (kv) vbar[z*HD + tid] = val;
        else    s_kb[tid] = val;
    }
    if (kv) return;
    __syncthreads();
    {
        const int wi = tid >> 3, jg = tid & 7;
        const float* qrow = &qsel[((size_t)z*T_KEEP + wi)*64 + jg*8];
        float4 q1 = *(const float4*)qrow;
        float4 q2 = *(const float4*)(qrow + 4);
        const int j0 = jg*8;
        float p = q1.x*s_kb[j0]   + q1.y*s_kb[j0+1] + q1.z*s_kb[j0+2] + q1.w*s_kb[j0+3]
                + q2.x*s_kb[j0+4] + q2.y*s_kb[j0+5] + q2.z*s_kb[j0+6] + q2.w*s_kb[j0+7];
        s_part[wi][jg] = p;
    }
    __syncthreads();
    if (tid < T_KEEP) {
        float sc = 0.f;
        #pragma unroll
        for (int gg = 0; gg < 8; ++gg) sc += s_part[tid][gg];
        sc *= 1.0f / (8.0f * expf(beta[h]));
        float m = sc;
        #pragma unroll
        for (int off = 16; off > 0; off >>= 1) m = fmaxf(m, __shfl_xor(m, off, 64));
        m = fmaxf(m, 0.f);                        // sink logit = 0
        float e = expf(sc - m);
        float d = e;
        #pragma unroll
        for (int off = 16; off > 0; off >>= 1) d += __shfl_xor(d, off, 64);
        d += expf(-m);                            // sink term
        float c = e / d;
        if (tid == T_KEEP-1) c += 1.0f;           // iter-0 contribution
        coef[z*T_KEEP + tid] = c;
    }
}

// ---- Kernel 3: fused G + output combine -------------------------------------
// grid 64 (b x 32 col-chunks of 16). out[b,wi,c] = bo[c] + sum_h coef*G[h,c]
__global__ __launch_bounds__(256) void gout(
    const float* __restrict__ coef, const float* __restrict__ vbar,
    const float* __restrict__ Wo, const float* __restrict__ bo,
    float* __restrict__ out)
{
    const int b  = blockIdx.x & 1;
    const int cc = blockIdx.x >> 1;      // 0..31
    const int tid = threadIdx.x;

    __shared__ float s_cf[NH][T_KEEP];
    __shared__ float s_vb[NH*HD];
    __shared__ float s_gp[16][NH][2];

    s_vb[tid]       = vbar[b*512 + tid];
    s_vb[tid + 256] = vbar[b*512 + 256 + tid];
    s_cf[tid >> 5][tid & 31] = coef[((size_t)(b*NH) + (tid >> 5))*T_KEEP + (tid & 31)];
    __syncthreads();

    {
        const int ci = tid & 15, hh = (tid >> 4) & 7, j2 = tid >> 7;
        const float* wr = &Wo[(size_t)(cc*16 + ci)*DM + hh*HD + j2*32];
        const float* vb = &s_vb[hh*HD + j2*32];
        float a = 0.f;
        #pragma unroll
        for (int j = 0; j < 32; j += 4) {
            float4 w4 = *(const float4*)&wr[j];
            a += w4.x*vb[j] + w4.y*vb[j+1] + w4.z*vb[j+2] + w4.w*vb[j+3];
        }
        s_gp[ci][hh][j2] = a;
    }
    __syncthreads();
    {
        const int ci = tid & 15;
        const float bov = bo[cc*16 + ci];
        #pragma unroll
        for (int hf = 0; hf < 2; ++hf) {
            const int wi = (tid >> 4) + hf*16;
            float v = bov;
            #pragma unroll
            for (int hh = 0; hh < NH; ++hh)
                v += s_cf[hh][wi] * (s_gp[ci][hh][0] + s_gp[ci][hh][1]);
            out[(size_t)(ROW0 + wi*2 + b)*DM + cc*16 + ci] = v;
        }
    }
}

extern "C" void kernel_launch(void* const* d_in, const int* in_sizes, int n_in,
                              void* d_out, int out_size, void* d_ws, size_t ws_size,
                              hipStream_t stream) {
    const float* x    = (const float*)d_in[0];
    const float* Wq   = (const float*)d_in[1];
    const float* bq   = (const float*)d_in[2];
    const float* Wk   = (const float*)d_in[3];
    const float* bk   = (const float*)d_in[4];
    const float* Wv   = (const float*)d_in[5];
    const float* bv   = (const float*)d_in[6];
    const float* Wo   = (const float*)d_in[7];
    const float* bo   = (const float*)d_in[8];
    const float* beta = (const float*)d_in[9];

    char* ws = (char*)d_ws;
    float* qsel = (float*)(ws + 0);               // 128 KB [z][32][64]
    float* sbar = (float*)(ws + 131072);          //  32 KB [z][512]
    float* Ssum = (float*)(ws + 163840);          //  64 B  [z]
    float* coef = (float*)(ws + 164096);          //   2 KB [z][32]
    float* vbar = (float*)(ws + 166144);          //   4 KB [z][64]
    short* xf   = (short*)(ws + 262144);          //   4 MB fp16 x
    short* wf   = (short*)(ws + 262144 + 4194304); // 1 MB fp16 [h][128][512]
    float* out  = (float*)d_out;

    convert<<<2048, 256, 0, stream>>>(x, Wq, Wk, bo, xf, wf, sbar, Ssum, out);
    qk_sig<<<256, 256, 0, stream>>>((const _Float16*)xf, (const _Float16*)wf, x,
                                    bq, bk, beta, sbar, Ssum, qsel);
    kvbar_coef<<<32, 256, 0, stream>>>(sbar, Ssum, Wk, bk, Wv, bv, qsel, beta, vbar, coef);
    gout<<<64, 256, 0, stream>>>(coef, vbar, Wo, bo, out);
}

// Round 2
// 113.022 us; speedup vs baseline: 1.1165x; 1.0033x over previous
//
#include <hip/hip_runtime.h>
#include <math.h>

#define S_LEN 2048
#define BSZ 2
#define DM 512
#define NH 8
#define HD 64
#define RTOT (S_LEN*BSZ)             // 4096 rows, row r = s*BSZ + b
#define T_KEEP 32
#define ROW0 ((S_LEN - T_KEEP)*BSZ)  // 4032
#define NXELEM (RTOT*DM)             // 2097152
#define NWROW  (NH*128)              // 1024 (per-head q|k rows)
#define NWELEM (NWROW*DM)            // 524288

typedef __attribute__((ext_vector_type(8))) _Float16 half8;
typedef __attribute__((ext_vector_type(4))) float floatx4;

__device__ __forceinline__ void gld16(const void* g, void* l) {
    __builtin_amdgcn_global_load_lds((const __attribute__((address_space(1))) void*)g,
                                     (__attribute__((address_space(3))) void*)l, 16, 0, 0);
}

__device__ __forceinline__ short cvt1(float v) {
    _Float16 h = (_Float16)v;
    return __builtin_bit_cast(short, h);
}

// ---- Kernel 0: fp32 -> fp16 planes (x, Wq|Wk per head) + zero sbar/Ssum + bg out fill
__global__ __launch_bounds__(256) void convert(
    const float* __restrict__ x,
    const float* __restrict__ Wq, const float* __restrict__ Wk,
    const float* __restrict__ bo,
    short* __restrict__ xf, short* __restrict__ wf,
    float* __restrict__ sbar, float* __restrict__ Ssum,
    float* __restrict__ out)
{
    const int g = blockIdx.x*blockDim.x + threadIdx.x;
    const int stride = gridDim.x*blockDim.x;
    const int total4 = (NXELEM + NWELEM)/4;
    for (int i = g; i < total4; i += stride) {
        float4 v; size_t dst; short* d;
        if (i < NXELEM/4) {
            v = ((const float4*)x)[i];
            dst = (size_t)i*4; d = xf;
        } else {
            int e = (i - NXELEM/4)*4;
            int R = e >> 9;                 // 0..1023: h*128 + (q:0-63 | k:64-127)
            int k = e & 511;
            int h = R >> 7;
            int p = R & 127;
            int m = p >> 6;                 // 0=q, 1=k
            int c = p & 63;
            const float* W = m ? Wk : Wq;
            v = *(const float4*)&W[(size_t)(h*HD + c)*DM + k];
            dst = (size_t)R*DM + k; d = wf;
        }
        short4 hv;
        hv.x = cvt1(v.x); hv.y = cvt1(v.y); hv.z = cvt1(v.z); hv.w = cvt1(v.w);
        *(short4*)&d[dst] = hv;
    }
    // background fill: rows < ROW0 of out are just bo
    {
        const float4* b4 = (const float4*)bo;
        float4* o4 = (float4*)out;
        const int fill4 = ROW0*DM/4;
        for (int i = g; i < fill4; i += stride) o4[i] = b4[i & 127];
    }
    if (g < 16*DM) sbar[g] = 0.f;     // 8192
    if (g < 16)    Ssum[g] = 0.f;
}

// ---- Kernel 1 (FUSED): per-head full q|k GEMM -> sigmoid -> sbar/Ssum/qsel ----
// grid 256 linear = (xcd-swizzled rc 0..31) x (h 0..7); 1 block/CU.
// Block handles 128 rows x all 128 j of one head. B staged in K-quarters
// (2x32KB LDS double-buffer). LDS layout: chunk c (1KB) = rows 4c..4c+3,
// 256B/row, 16 slots of 16B. Slot position p of global slot s in row j is
// p = s ^ (j&15)  -- a FULL 4-bit XOR so each 16-lane ds_read phase hits all
// 8 bank groups uniformly (the R1 version used only j&3 -> 4-way conflicts).
// Store side realizes this by pre-swizzling the global source per chunk:
// lane l of chunk i fetches slot (l&15) ^ jsub ^ ((i&3)<<2), row 4i+jsub.
__global__ __launch_bounds__(256, 1) void qk_sig(
    const _Float16* __restrict__ xf, const _Float16* __restrict__ wf,
    const float* __restrict__ x,
    const float* __restrict__ bq, const float* __restrict__ bk,
    const float* __restrict__ beta,
    float* __restrict__ sbar, float* __restrict__ Ssum,
    float* __restrict__ qsel)
{
    __shared__ __align__(16) char smem[65536];   // 2 x 32KB B quarters; reused for sigma

    const int tid  = threadIdx.x;
    const int w    = tid >> 6;
    const int lane = tid & 63;
    const int lrow = lane & 15;
    const int lk8  = lane >> 4;
    const int bid  = blockIdx.x;
    // XCD-contiguous rc: xcd = bid&7 gets rc in [xcd*4, xcd*4+4) -> xf stays in that XCD's L2
    const int rc   = (bid & 7)*4 + (bid >> 6);
    const int h    = (bid >> 3) & 7;
    const int r0   = rc * 128;

    const int jsub  = lk8;                          // 0..3: row within chunk
    const int pbase = lrow ^ jsub;                  // lane's base slot (chunk-i adds (i&3)<<2)
    const _Float16* wbase = wf + (size_t)(h*128 + w*32 + jsub)*DM;

    // prologue: stage quarter 0 (chunk i: rows 4i.., slot pbase^((i&3)<<2))
    #pragma unroll
    for (int i = 0; i < 8; ++i)
        gld16(wbase + (size_t)(4*i)*DM + (pbase ^ ((i&3)<<2))*8,
              smem + (w*8 + i)*1024);

    const int rbA = r0 + w*16;
    const int rbB = r0 + (w+4)*16;
    const _Float16* paA = xf + (size_t)(rbA + lrow)*DM + lk8*8;
    const _Float16* paB = xf + (size_t)(rbB + lrow)*DM + lk8*8;

    floatx4 acc[2][8];
    #pragma unroll
    for (int jt = 0; jt < 8; ++jt) { acc[0][jt] = (floatx4)0.f; acc[1][jt] = (floatx4)0.f; }

    half8 Aa[2][4], Ab[2][4];
    #pragma unroll
    for (int kc2 = 0; kc2 < 4; ++kc2) {
        Aa[0][kc2] = *(const half8*)(paA + kc2*32);
        Ab[0][kc2] = *(const half8*)(paB + kc2*32);
    }

    __syncthreads();

    #pragma unroll
    for (int kq = 0; kq < 4; ++kq) {
        const int cur = kq & 1, nxt = cur ^ 1;
        if (kq < 3) {
            // prefetch next-quarter A (regs) and B (LDS) BEFORE MFMAs
            #pragma unroll
            for (int kc2 = 0; kc2 < 4; ++kc2) {
                Aa[nxt][kc2] = *(const half8*)(paA + ((kq+1)*4 + kc2)*32);
                Ab[nxt][kc2] = *(const half8*)(paB + ((kq+1)*4 + kc2)*32);
            }
            char* nb = smem + nxt*32768;
            #pragma unroll
            for (int i = 0; i < 8; ++i)
                gld16(wbase + (size_t)(4*i)*DM + (size_t)(kq+1)*128
                            + (pbase ^ ((i&3)<<2))*8,
                      nb + (w*8 + i)*1024);
        }
        const char* buf = smem + cur*32768;
        #pragma unroll
        for (int kc2 = 0; kc2 < 4; ++kc2) {
            #pragma unroll
            for (int jt = 0; jt < 8; ++jt) {
                const int j = jt*16 + lrow;
                const int slotp = (kc2*4 + lk8) ^ lrow;   // p = s ^ (j&15)
                half8 bf = *(const half8*)(buf + j*256 + slotp*16);
                acc[0][jt] = __builtin_amdgcn_mfma_f32_16x16x32_f16(Aa[cur][kc2], bf, acc[0][jt], 0, 0, 0);
                acc[1][jt] = __builtin_amdgcn_mfma_f32_16x16x32_f16(Ab[cur][kc2], bf, acc[1][jt], 0, 0, 0);
            }
        }
        __syncthreads();
    }

    // ---- epilogue: sigma = sigmoid((q+bq).(k+bk) * isc); qsel for selected rows
    float* s_sig = (float*)smem;     // B no longer needed; reuse LDS
    float bqv[4], bkv[4];
    #pragma unroll
    for (int jt = 0; jt < 4; ++jt) {
        bqv[jt] = bq[h*HD + jt*16 + lrow];
        bkv[jt] = bk[h*HD + jt*16 + lrow];
    }
    const float isc = 1.0f / (8.0f * expf(beta[h]));

    #pragma unroll
    for (int t = 0; t < 2; ++t) {
        #pragma unroll
        for (int r = 0; r < 4; ++r) {
            float q[4]; float p = 0.f;
            #pragma unroll
            for (int jt = 0; jt < 4; ++jt) {
                float qv = acc[t][jt][r]   + bqv[jt];
                float kv = acc[t][jt+4][r] + bkv[jt];
                q[jt] = qv;
                p += qv * kv;
            }
            p += __shfl_xor(p, 1, 64);
            p += __shfl_xor(p, 2, 64);
            p += __shfl_xor(p, 4, 64);
            p += __shfl_xor(p, 8, 64);
            const int rowl = (w + t*4)*16 + lk8*4 + r;    // 0..127 within block
            if (lrow == 0)
                s_sig[rowl] = 1.0f / (1.0f + expf(-p * isc));
            if (rowl >= 126) {                            // s%64==63 rows (b=0,1)
                const int b = rowl & 1;
                float* qd = &qsel[((size_t)((b*NH + h)*T_KEEP) + rc)*64];
                #pragma unroll
                for (int jt = 0; jt < 4; ++jt) qd[jt*16 + lrow] = q[jt];
            }
        }
    }
    __syncthreads();

    // ---- sbar partial from fp32 x (L2-hot rows); thread = (b, 4-col group)
    {
        const int b  = tid & 1;
        const int cg = tid >> 1;
        const float* px = x + (size_t)(r0 + b)*DM + cg*4;
        float a0=0.f, a1=0.f, a2=0.f, a3=0.f;
        #pragma unroll 8
        for (int si = 0; si < 64; ++si) {
            const float sg = s_sig[si*2 + b];
            const float4 xv = *(const float4*)(px + (size_t)(si*2)*DM);
            a0 += sg*xv.x; a1 += sg*xv.y; a2 += sg*xv.z; a3 += sg*xv.w;
        }
        float* sd = &sbar[(size_t)(b*NH + h)*DM + cg*4];
        atomicAdd(sd+0, a0); atomicAdd(sd+1, a1);
        atomicAdd(sd+2, a2); atomicAdd(sd+3, a3);
    }
    if (tid < 2) {
        float s = 0.f;
        for (int i = 0; i < 64; ++i) s += s_sig[i*2 + tid];
        atomicAdd(&Ssum[tid*NH + h], s);
    }
}

// ---- Kernel 2: kbar/vbar = W*sbar + b*S; coef softmax (kv=0 blocks) ----------
// grid 32 (z x {k,v}), block 256.
__global__ __launch_bounds__(256) void kvbar_coef(
    const float* __restrict__ sbar, const float* __restrict__ Ssum,
    const float* __restrict__ Wk, const float* __restrict__ bk,
    const float* __restrict__ Wv, const float* __restrict__ bv,
    const float* __restrict__ qsel, const float* __restrict__ beta,
    float* __restrict__ vbar, float* __restrict__ coef)
{
    const int z  = blockIdx.x >> 1;
    const int kv = blockIdx.x & 1;
    const int h  = z & 7;
    const int tid = threadIdx.x;

    __shared__ float s_sb[DM];
    __shared__ float s_red[64][4];
    __shared__ float s_kb[64];
    __shared__ float s_part[T_KEEP][8];

    s_sb[tid]       = sbar[z*DM + tid];
    s_sb[tid + 256] = sbar[z*DM + 256 + tid];
    __syncthreads();
    const float S = Ssum[z];

    const float* W    = kv ? Wv : Wk;
    const float* bvec = kv ? bv : bk;
    {
        const int j = tid >> 2, kp = tid & 3;
        const float* wr = &W[(size_t)(h*HD + j)*DM + kp*128];
        float a = 0.f;
        #pragma unroll
        for (int k = 0; k < 128; k += 4) {
            float4 w4 = *(const float4*)&wr[k];
            int k0 = kp*128 + k;
            a += w4.x*s_sb[k0] + w4.y*s_sb[k0+1] + w4.z*s_sb[k0+2] + w4.w*s_sb[k0+3];
        }
        s_red[j][kp] = a;
    }
    __syncthreads();
    if (tid < 64) {
        float val = s_red[tid][0]+s_red[tid][1]+s_red[tid][2]+s_red[tid][3]
                  + bvec[h*HD + tid]*S;
        if (kv) vbar[z*HD + tid] = val;
        else    s_kb[tid] = val;
    }
    if (kv) return;
    __syncthreads();
    {
        const int wi = tid >> 3, jg = tid & 7;
        const float* qrow = &qsel[((size_t)z*T_KEEP + wi)*64 + jg*8];
        float4 q1 = *(const float4*)qrow;
        float4 q2 = *(const float4*)(qrow + 4);
        const int j0 = jg*8;
        float p = q1.x*s_kb[j0]   + q1.y*s_kb[j0+1] + q1.z*s_kb[j0+2] + q1.w*s_kb[j0+3]
                + q2.x*s_kb[j0+4] + q2.y*s_kb[j0+5] + q2.z*s_kb[j0+6] + q2.w*s_kb[j0+7];
        s_part[wi][jg] = p;
    }
    __syncthreads();
    if (tid < T_KEEP) {
        float sc = 0.f;
        #pragma unroll
        for (int gg = 0; gg < 8; ++gg) sc += s_part[tid][gg];
        sc *= 1.0f / (8.0f * expf(beta[h]));
        float m = sc;
        #pragma unroll
        for (int off = 16; off > 0; off >>= 1) m = fmaxf(m, __shfl_xor(m, off, 64));
        m = fmaxf(m, 0.f);                        // sink logit = 0
        float e = expf(sc - m);
        float d = e;
        #pragma unroll
        for (int off = 16; off > 0; off >>= 1) d += __shfl_xor(d, off, 64);
        d += expf(-m);                            // sink term
        float c = e / d;
        if (tid == T_KEEP-1) c += 1.0f;           // iter-0 contribution
        coef[z*T_KEEP + tid] = c;
    }
}

// ---- Kernel 3: fused G + output combine -------------------------------------
// grid 64 (b x 32 col-chunks of 16). out[b,wi,c] = bo[c] + sum_h coef*G[h,c]
__global__ __launch_bounds__(256) void gout(
    const float* __restrict__ coef, const float* __restrict__ vbar,
    const float* __restrict__ Wo, const float* __restrict__ bo,
    float* __restrict__ out)
{
    const int b  = blockIdx.x & 1;
    const int cc = blockIdx.x >> 1;      // 0..31
    const int tid = threadIdx.x;

    __shared__ float s_cf[NH][T_KEEP];
    __shared__ float s_vb[NH*HD];
    __shared__ float s_gp[16][NH][2];

    s_vb[tid]       = vbar[b*512 + tid];
    s_vb[tid + 256] = vbar[b*512 + 256 + tid];
    s_cf[tid >> 5][tid & 31] = coef[((size_t)(b*NH) + (tid >> 5))*T_KEEP + (tid & 31)];
    __syncthreads();

    {
        const int ci = tid & 15, hh = (tid >> 4) & 7, j2 = tid >> 7;
        const float* wr = &Wo[(size_t)(cc*16 + ci)*DM + hh*HD + j2*32];
        const float* vb = &s_vb[hh*HD + j2*32];
        float a = 0.f;
        #pragma unroll
        for (int j = 0; j < 32; j += 4) {
            float4 w4 = *(const float4*)&wr[j];
            a += w4.x*vb[j] + w4.y*vb[j+1] + w4.z*vb[j+2] + w4.w*vb[j+3];
        }
        s_gp[ci][hh][j2] = a;
    }
    __syncthreads();
    {
        const int ci = tid & 15;
        const float bov = bo[cc*16 + ci];
        #pragma unroll
        for (int hf = 0; hf < 2; ++hf) {
            const int wi = (tid >> 4) + hf*16;
            float v = bov;
            #pragma unroll
            for (int hh = 0; hh < NH; ++hh)
                v += s_cf[hh][wi] * (s_gp[ci][hh][0] + s_gp[ci][hh][1]);
            out[(size_t)(ROW0 + wi*2 + b)*DM + cc*16 + ci] = v;
        }
    }
}

extern "C" void kernel_launch(void* const* d_in, const int* in_sizes, int n_in,
                              void* d_out, int out_size, void* d_ws, size_t ws_size,
                              hipStream_t stream) {
    const float* x    = (const float*)d_in[0];
    const float* Wq   = (const float*)d_in[1];
    const float* bq   = (const float*)d_in[2];
    const float* Wk   = (const float*)d_in[3];
    const float* bk   = (const float*)d_in[4];
    const float* Wv   = (const float*)d_in[5];
    const float* bv   = (const float*)d_in[6];
    const float* Wo   = (const float*)d_in[7];
    const float* bo   = (const float*)d_in[8];
    const float* beta = (const float*)d_in[9];

    char* ws = (char*)d_ws;
    float* qsel = (float*)(ws + 0);               // 128 KB [z][32][64]
    float* sbar = (float*)(ws + 131072);          //  32 KB [z][512]
    float* Ssum = (float*)(ws + 163840);          //  64 B  [z]
    float* coef = (float*)(ws + 164096);          //   2 KB [z][32]
    float* vbar = (float*)(ws + 166144);          //   4 KB [z][64]
    short* xf   = (short*)(ws + 262144);          //   4 MB fp16 x
    short* wf   = (short*)(ws + 262144 + 4194304); // 1 MB fp16 [h][128][512]
    float* out  = (float*)d_out;

    convert<<<2048, 256, 0, stream>>>(x, Wq, Wk, bo, xf, wf, sbar, Ssum, out);
    qk_sig<<<256, 256, 0, stream>>>((const _Float16*)xf, (const _Float16*)wf, x,
                                    bq, bk, beta, sbar, Ssum, qsel);
    kvbar_coef<<<32, 256, 0, stream>>>(sbar, Ssum, Wk, bk, Wv, bv, qsel, beta, vbar, coef);
    gout<<<64, 256, 0, stream>>>(coef, vbar, Wo, bo, out);
}